// Round 15
// baseline (399.618 us; speedup 1.0000x reference)
//
#include <hip/hip_runtime.h>
#include <hip/hip_bf16.h>
#include <stdint.h>
#include <math.h>

// Problem constants
#define NB 4
#define NT 2048
#define NC 2048
#define NH 16
#define HD 128
#define BT (NB*NT)   // 8192

typedef __attribute__((ext_vector_type(8))) short s16x8;
typedef __attribute__((ext_vector_type(4))) short s16x4;
typedef __attribute__((ext_vector_type(4))) float f32x4;

typedef __attribute__((address_space(1))) void as1_void;
typedef __attribute__((address_space(3))) void as3_void;

static __device__ __forceinline__ unsigned short f2bf(float f) {
  union { float f; uint32_t u; } v; v.f = f;
  return (unsigned short)((v.u + 0x7fffu + ((v.u >> 16) & 1u)) >> 16);
}
static __device__ __forceinline__ float bf2f(unsigned short u) {
  union { uint32_t u; float f; } v; v.u = ((uint32_t)u) << 16;
  return v.f;
}
static __device__ __forceinline__ void async16(unsigned short* lds, const unsigned short* g) {
  __builtin_amdgcn_global_load_lds((as1_void*)g, (as3_void*)lds, 16, 0, 0);
}
static __device__ __forceinline__ uint32_t lds_off(void* p) {
  return (uint32_t)(size_t)(as3_void*)p;
}

// ---------------- fused prep: convert x->bf16  +  transpose Wqkv, Wproj ----------------
// One dispatch, blockIdx partition; parts co-run so small-kernel tails and two
// launch gaps disappear. Inner code identical to the proven per-kernel versions.
__global__ void k_prep(const float* __restrict__ x, unsigned short* __restrict__ xb,
                       const float* __restrict__ Wqkv, unsigned short* __restrict__ WqkvT,
                       const float* __restrict__ Wproj, unsigned short* __restrict__ WprojT) {
  __shared__ unsigned short tile[64][65];
  const int blk = blockIdx.x;
  const int t = threadIdx.x;
  if (blk < 8192) {
    // convert: 8 elems/thread
    const int i = blk * 256 + t;
    const float4* p = (const float4*)x + (size_t)i * 2;
    float4 a = p[0], b = p[1];
    union { unsigned short s[8]; uint4 u; } o;
    o.s[0] = f2bf(a.x); o.s[1] = f2bf(a.y); o.s[2] = f2bf(a.z); o.s[3] = f2bf(a.w);
    o.s[4] = f2bf(b.x); o.s[5] = f2bf(b.y); o.s[6] = f2bf(b.z); o.s[7] = f2bf(b.w);
    ((uint4*)xb)[i] = o.u;
    return;
  }
  const float* W;
  unsigned short* WT;
  int bx, by, N;
  if (blk < 8192 + 3072) {
    const int id = blk - 8192;
    W = Wqkv; WT = WqkvT; N = 3 * NC; bx = id % 96; by = id / 96;
  } else {
    const int id = blk - 11264;
    W = Wproj; WT = WprojT; N = NC; bx = id % 32; by = id / 32;
  }
  const int K = NC;
  const int k0 = by * 64, n0 = bx * 64;
  const int jj = t & 63, base_i = t >> 6;
  #pragma unroll
  for (int p = 0; p < 16; ++p) {
    int i = p * 4 + base_i;
    tile[i][jj] = f2bf(W[(size_t)(k0 + i) * N + n0 + jj]);
  }
  __syncthreads();
  #pragma unroll
  for (int p = 0; p < 16; ++p) {
    int j = p * 4 + base_i;
    WT[(size_t)(n0 + j) * K + k0 + jj] = tile[jj][j];
  }
}

// ---------------- GEMM 256x128 block, BK=64, 256 thr / 4 waves (2Mx2N) ----------------
// FROZEN core (session GEMM optimum): wave tile 128x64, LDS 48 KiB, 2 blocks/CU,
// 2-phase __syncthreads, chunk-XOR swizzle (0 conflicts), natural blockIdx.
// __launch_bounds__(256,2) MANDATORY (r3/r8 spills). Structural ledger: r5 4-phase,
// r6 256², r12 ring-3 all regressed — do not re-attempt without the full m201 template.
// MODE 0: scatter bf16 Q/K/V [B][H][T][D] with FUSED RoPE for Q/K — partner value
// (d, d+64) lives in wave wn^1 (same lane/regs); 2-barrier LDS exchange per 2-mi
// chunk through the dead Al buffer. RoPE angles via ONE __sincosf per (mi,ni) +
// rotation recurrence over r (tp increments by 1; never crosses a 2048 boundary
// since tpb == lg*4 mod 16). Q additionally scaled by (1/sqrt(128))*log2e.
// MODE 1: fp32 row-major out.
template<int MODE>
__global__ __launch_bounds__(256, 2)
void k_gemm_bt2(const unsigned short* __restrict__ A,
                const unsigned short* __restrict__ Bt,
                const float* __restrict__ bias,
                float* __restrict__ OutF,
                unsigned short* __restrict__ Qd,
                unsigned short* __restrict__ Kd,
                unsigned short* __restrict__ Vd,
                int M, int N, int K)
{
  __shared__ __align__(16) unsigned short Al[256 * 64];
  __shared__ __align__(16) unsigned short Bl[128 * 64];
  const int t = threadIdx.x;
  const int l = t & 63;
  const int wv = t >> 6;
  const int wm = wv >> 1, wn = wv & 1;     // 2 x 2 wave grid; wave tile 128x64
  const int bm = blockIdx.y * 256, bn = blockIdx.x * 128;
  const int lr = l & 15, lg = l >> 4;

  f32x4 acc[8][4];
  #pragma unroll
  for (int i = 0; i < 8; ++i)
    #pragma unroll
    for (int j = 0; j < 4; ++j)
      acc[i][j] = f32x4{0.f, 0.f, 0.f, 0.f};

  for (int k0 = 0; k0 < K; k0 += 64) {
    // stage A 256x64 (2048 chunks, 8 rounds) + B 128x64 (1024 chunks, 4 rounds)
    #pragma unroll
    for (int i = 0; i < 8; ++i) {
      const int Cc = i * 256 + t;          // 16B chunk id
      const int row = Cc >> 3;
      const int kc = (Cc & 7) ^ (row & 7);
      async16(&Al[(i * 256 + (t & 192)) * 8], &A[(size_t)(bm + row) * K + k0 + kc * 8]);
    }
    #pragma unroll
    for (int i = 0; i < 4; ++i) {
      const int Cc = i * 256 + t;
      const int row = Cc >> 3;
      const int kc = (Cc & 7) ^ (row & 7);
      async16(&Bl[(i * 256 + (t & 192)) * 8], &Bt[(size_t)(bn + row) * K + k0 + kc * 8]);
    }
    __syncthreads();
    #pragma unroll
    for (int kk = 0; kk < 2; ++kk) {
      s16x8 af[8], bfr[4];
      #pragma unroll
      for (int mi = 0; mi < 8; ++mi) {
        const int row = wm * 128 + mi * 16 + lr;
        const int ch = (kk * 4 + lg) ^ (row & 7);
        af[mi] = *(const s16x8*)&Al[row * 64 + ch * 8];
      }
      #pragma unroll
      for (int ni = 0; ni < 4; ++ni) {
        const int row = wn * 64 + ni * 16 + lr;
        const int ch = (kk * 4 + lg) ^ (row & 7);
        bfr[ni] = *(const s16x8*)&Bl[row * 64 + ch * 8];
      }
      __builtin_amdgcn_s_setprio(1);
      #pragma unroll
      for (int mi = 0; mi < 8; ++mi)
        #pragma unroll
        for (int ni = 0; ni < 4; ++ni)
          acc[mi][ni] = __builtin_amdgcn_mfma_f32_16x16x32_bf16(af[mi], bfr[ni], acc[mi][ni], 0, 0, 0);
      __builtin_amdgcn_s_setprio(0);
    }
    __syncthreads();
  }

  // epilogue; C/D layout: col = lane&15, row = (lane>>4)*4 + reg  [m89-verified]
  if (MODE == 1) {
    #pragma unroll
    for (int mi = 0; mi < 8; ++mi) {
      #pragma unroll
      for (int ni = 0; ni < 4; ++ni) {
        const int col = bn + wn * 64 + ni * 16 + lr;
        const float bv = bias[col];
        #pragma unroll
        for (int r = 0; r < 4; ++r) {
          const int row = bm + wm * 128 + mi * 16 + lg * 4 + r;
          OutF[(size_t)row * N + col] = acc[mi][ni][r] + bv;
        }
      }
    }
  } else {
    const int whichB = bn >> 11;            // 0=q 1=k 2=v (block-uniform: panel 128-aligned)
    const int bb = bm >> 11;                // batch (block-uniform: 2048%256==0)
    const int h = (bn & 2047) >> 7;         // head (block-uniform)
    unsigned short* dst = (whichB == 0) ? Qd : (whichB == 1 ? Kd : Vd);
    if (whichB == 2) {
      // V: plain scatter
      #pragma unroll
      for (int mi = 0; mi < 8; ++mi) {
        #pragma unroll
        for (int ni = 0; ni < 4; ++ni) {
          const int col = bn + wn * 64 + ni * 16 + lr;
          const float bv = bias[col];
          const int d = wn * 64 + ni * 16 + lr;
          #pragma unroll
          for (int r = 0; r < 4; ++r) {
            const int tp = (bm + wm * 128 + mi * 16 + lg * 4 + r) & 2047;
            dst[(((size_t)(bb * NH + h)) * NT + tp) * HD + d] = f2bf(acc[mi][ni][r] + bv);
          }
        }
      }
    } else {
      // Q/K: fused RoPE. own pairs with partner wave wn^1 (same lane, same regs).
      const float qsc = (whichB == 0) ? (0.08838834764831845f * 1.4426950408889634f) : 1.0f;
      float invf[4], crot[4], srot[4];
      #pragma unroll
      for (int ni = 0; ni < 4; ++ni) {
        invf[ni] = exp2f(-(float)(ni * 16 + lr) * 0.2076205059304602f);  // log2(10000)/64
        __sincosf(invf[ni], &srot[ni], &crot[ni]);   // per-step rotation (delta tp = 1)
      }
      float* Ex = (float*)Al;               // 8192 floats, dead after K-loop
      #pragma unroll
      for (int mc = 0; mc < 4; ++mc) {      // mi chunk {2mc, 2mc+1}
        __syncthreads();
        #pragma unroll
        for (int dm = 0; dm < 2; ++dm)
          #pragma unroll
          for (int ni = 0; ni < 4; ++ni) {
            const float bv = bias[bn + wn * 64 + ni * 16 + lr];
            #pragma unroll
            for (int r = 0; r < 4; ++r)
              Ex[(dm * 16 + ni * 4 + r) * 256 + wv * 64 + l] = acc[mc * 2 + dm][ni][r] + bv;
          }
        __syncthreads();
        #pragma unroll
        for (int dm = 0; dm < 2; ++dm) {
          const int mi = mc * 2 + dm;
          const int tpb = (bm + wm * 128 + mi * 16 + lg * 4) & 2047;
          #pragma unroll
          for (int ni = 0; ni < 4; ++ni) {
            const float bv = bias[bn + wn * 64 + ni * 16 + lr];
            const int d = wn * 64 + ni * 16 + lr;
            float s, c;
            __sincosf((float)tpb * invf[ni], &s, &c);
            #pragma unroll
            for (int r = 0; r < 4; ++r) {
              const int tp = tpb + r;       // same 16-block: no 2048 wrap possible
              const float own = acc[mi][ni][r] + bv;
              const float oth = Ex[(dm * 16 + ni * 4 + r) * 256 + (wv ^ 1) * 64 + l];
              const float out = ((wn == 0) ? (own * c - oth * s) : (own * c + oth * s)) * qsc;
              dst[(((size_t)(bb * NH + h)) * NT + tp) * HD + d] = f2bf(out);
              const float cn = c * crot[ni] - s * srot[ni];   // rotate by invf[ni]
              s = s * crot[ni] + c * srot[ni];
              c = cn;
            }
          }
        }
      }
    }
  }
}

// ---------------- flash attention: 4 waves x 32 q-rows (2 frags), KV tile 64, dbuf ----------------
// Each lane owns TWO q-rows; K-frag LDS reads, V tr-reads, and KV staging SHARED
// across both fragments. Block = 128 q-rows; grid (bh 64, pair 8); pair balance
// (i, 15-i) -> 34 kv-iters const; same-head blocks on one XCD.
// swapped S^T = mfma(K, Q); T13 defer-max; cvt_pk P-pack; packed 8B output stores.
// Final tile skipped by waves 0,1 (fully causal-masked there — exact-zero contribution).
__global__ __launch_bounds__(256, 2)
void k_attn(const unsigned short* __restrict__ Q,
            const unsigned short* __restrict__ Kg,
            const unsigned short* __restrict__ Vg,
            unsigned short* __restrict__ Yatt)   // att [BT][NC] bf16
{
  __shared__ __align__(16) unsigned short Kl[2][64 * 128];  // [key][d], 16B-chunk-swizzled
  __shared__ __align__(16) unsigned short Vl[2][64 * 128];  // subtiled [key/4][d/16][4][16]
  const int bh = blockIdx.x;          // 0..63
  const int pair = blockIdx.y;        // 0..7
  const int b = bh >> 4, h = bh & 15;
  const int t = threadIdx.x, l = t & 63, wv = t >> 6;
  const int lr = l & 15, lg = l >> 4;
  const size_t hoff = (size_t)bh * NT * HD;
  const unsigned short* Qh = Q + hoff;
  const unsigned short* Kh = Kg + hoff;
  const unsigned short* Vh = Vg + hoff;
  const uint32_t vbase0 = lds_off(&Vl[0][0]);

  auto stageKV = [&](int buf, int kv0) {
    #pragma unroll
    for (int i = 0; i < 4; ++i) {
      const int Cc = i * 256 + t;
      {  // K tile: row-major [64][128], 16B chunks swizzled with (row&7)
        const int krow = Cc >> 4;
        const int kc = (Cc & 15) ^ (krow & 7);
        async16(&Kl[buf][(i * 256 + (t & 192)) * 8], &Kh[(size_t)(kv0 + krow) * HD + kc * 8]);
      }
      {  // V tile: subtile S = kq*8+dq holds [4 keys][16 d] row-major
        const int S = Cc >> 3, c8 = Cc & 7;
        const int kq = S >> 3, dq = S & 7;
        const int vk = kq * 4 + (c8 >> 1), vd = dq * 16 + (c8 & 1) * 8;
        async16(&Vl[buf][(i * 256 + (t & 192)) * 8], &Vh[(size_t)(kv0 + vk) * HD + vd]);
      }
    }
  };

  #pragma unroll 1
  for (int rep = 0; rep < 2; ++rep) {
    const int qb16 = rep ? (15 - pair) : pair;   // q-tile of 128 rows
    const int q0w = qb16 * 128 + wv * 32;        // wave's 32-row strip
    const int qrowA = q0w + lr, qrowB = q0w + 16 + lr;

    __syncthreads();  // protect LDS reuse across reps

    s16x8 qfA[4], qfB[4];
    #pragma unroll
    for (int m = 0; m < 4; ++m) {
      qfA[m] = *(const s16x8*)(Qh + (size_t)qrowA * HD + m * 32 + lg * 8);
      qfB[m] = *(const s16x8*)(Qh + (size_t)qrowB * HD + m * 32 + lg * 8);
    }

    f32x4 ytA[8], ytB[8];
    #pragma unroll
    for (int n = 0; n < 8; ++n) { ytA[n] = f32x4{0.f,0.f,0.f,0.f}; ytB[n] = f32x4{0.f,0.f,0.f,0.f}; }
    float mrunA = -1e30f, lrunA = 0.f, mrunB = -1e30f, lrunB = 0.f;

    auto computeTile = [&](int buf, int kv0) {
      // S^T tiles for both q-frags; K frags shared
      f32x4 stA[4], stB[4];
      __builtin_amdgcn_s_setprio(1);
      #pragma unroll
      for (int kt = 0; kt < 4; ++kt) {
        f32x4 a = f32x4{0.f,0.f,0.f,0.f}, bq = f32x4{0.f,0.f,0.f,0.f};
        const int krow = kt * 16 + lr;
        #pragma unroll
        for (int m = 0; m < 4; ++m) {
          const int ch = (m * 4 + lg) ^ (krow & 7);
          s16x8 kf = *(const s16x8*)&Kl[buf][krow * 128 + ch * 8];
          a  = __builtin_amdgcn_mfma_f32_16x16x32_bf16(kf, qfA[m], a, 0, 0, 0);
          bq = __builtin_amdgcn_mfma_f32_16x16x32_bf16(kf, qfB[m], bq, 0, 0, 0);
        }
        stA[kt] = a; stB[kt] = bq;
      }
      __builtin_amdgcn_s_setprio(0);

      // causal mask near diagonal (per frag)
      if (kv0 + 63 > q0w) {
        #pragma unroll
        for (int kt = 0; kt < 4; ++kt)
          #pragma unroll
          for (int r = 0; r < 4; ++r) {
            const int key = kv0 + kt * 16 + lg * 4 + r;
            if (key > qrowA) stA[kt][r] = -3.0e38f;
            if (key > qrowB) stB[kt][r] = -3.0e38f;
          }
      }

      // online softmax x2 (T13 defer-max)
      float tmA = -3.0e38f, tmB = -3.0e38f;
      #pragma unroll
      for (int kt = 0; kt < 4; ++kt)
        #pragma unroll
        for (int r = 0; r < 4; ++r) { tmA = fmaxf(tmA, stA[kt][r]); tmB = fmaxf(tmB, stB[kt][r]); }
      tmA = fmaxf(tmA, __shfl_xor(tmA, 16)); tmA = fmaxf(tmA, __shfl_xor(tmA, 32));
      tmB = fmaxf(tmB, __shfl_xor(tmB, 16)); tmB = fmaxf(tmB, __shfl_xor(tmB, 32));
      if (!__all((tmA - mrunA <= 8.0f) && (tmB - mrunB <= 8.0f))) {
        const float mnA = fmaxf(mrunA, tmA), mnB = fmaxf(mrunB, tmB);
        const float fsA = exp2f(mrunA - mnA), fsB = exp2f(mrunB - mnB);
        mrunA = mnA; mrunB = mnB;
        lrunA *= fsA; lrunB *= fsB;
        #pragma unroll
        for (int n = 0; n < 8; ++n)
          #pragma unroll
          for (int r = 0; r < 4; ++r) { ytA[n][r] *= fsA; ytB[n][r] *= fsB; }
      }

      float pvA[16], pvB[16];
      float psA = 0.f, psB = 0.f;
      #pragma unroll
      for (int kt = 0; kt < 4; ++kt)
        #pragma unroll
        for (int r = 0; r < 4; ++r) {
          const float pa = exp2f(stA[kt][r] - mrunA);
          const float pb = exp2f(stB[kt][r] - mrunB);
          psA += pa; psB += pb;
          pvA[kt * 4 + r] = pa; pvB[kt * 4 + r] = pb;
        }
      lrunA += psA; lrunB += psB;

      // pack P^T frags via v_cvt_pk_bf16_f32
      union { uint32_t w[4]; s16x8 v; } puA[2], puB[2];
      #pragma unroll
      for (int gk = 0; gk < 2; ++gk)
        #pragma unroll
        for (int w = 0; w < 4; ++w) {
          const int i0 = (gk * 2 + (w >> 1)) * 4 + (w & 1) * 2;
          asm("v_cvt_pk_bf16_f32 %0, %1, %2" : "=v"(puA[gk].w[w]) : "v"(pvA[i0]), "v"(pvA[i0 + 1]));
          asm("v_cvt_pk_bf16_f32 %0, %1, %2" : "=v"(puB[gk].w[w]) : "v"(pvB[i0]), "v"(pvB[i0 + 1]));
        }

      // PV: V^T frags shared across both q-frags
      const uint32_t vb = vbase0 + (uint32_t)buf * 16384;
      #pragma unroll
      for (int gk = 0; gk < 2; ++gk) {
        s16x4 va[8], vb2[8];
        #pragma unroll
        for (int n = 0; n < 8; ++n) {
          const uint32_t a0 = vb + ((uint32_t)((gk * 8 + lg) * 8 + n)) * 128 + (uint32_t)lr * 8;
          asm volatile("ds_read_b64_tr_b16 %0, %1" : "=v"(va[n])  : "v"(a0));
          asm volatile("ds_read_b64_tr_b16 %0, %1" : "=v"(vb2[n]) : "v"(a0 + 4096));
        }
        asm volatile("s_waitcnt lgkmcnt(0)" ::: "memory");
        __builtin_amdgcn_sched_barrier(0);
        __builtin_amdgcn_s_setprio(1);
        #pragma unroll
        for (int n = 0; n < 8; ++n) {
          s16x8 vf;
          vf[0] = va[n][0];  vf[1] = va[n][1];  vf[2] = va[n][2];  vf[3] = va[n][3];
          vf[4] = vb2[n][0]; vf[5] = vb2[n][1]; vf[6] = vb2[n][2]; vf[7] = vb2[n][3];
          ytA[n] = __builtin_amdgcn_mfma_f32_16x16x32_bf16(vf, puA[gk].v, ytA[n], 0, 0, 0);
          ytB[n] = __builtin_amdgcn_mfma_f32_16x16x32_bf16(vf, puB[gk].v, ytB[n], 0, 0, 0);
        }
        __builtin_amdgcn_s_setprio(0);
      }
    };

    const int nkv = 2 * qb16 + 2;
    stageKV(0, 0);
    asm volatile("s_waitcnt vmcnt(0)" ::: "memory");
    __syncthreads();
    int buf = 0;
    #pragma unroll 1
    for (int kv = 0; kv < nkv - 1; ++kv) {
      stageKV(buf ^ 1, (kv + 1) * 64);      // issue next tile's loads first
      computeTile(buf, kv * 64);            // overlap compute with loads
      asm volatile("s_waitcnt vmcnt(0)" ::: "memory");
      __builtin_amdgcn_s_barrier();
      buf ^= 1;
    }
    if ((nkv - 1) * 64 <= q0w + 31)         // waves 0,1: final tile fully masked -> skip
      computeTile(buf, (nkv - 1) * 64);

    // finalize both frags: reduce l, scale, packed 8B stores
    lrunA += __shfl_xor(lrunA, 16); lrunA += __shfl_xor(lrunA, 32);
    lrunB += __shfl_xor(lrunB, 16); lrunB += __shfl_xor(lrunB, 32);
    const float invA = 1.f / lrunA, invB = 1.f / lrunB;
    unsigned short* yrowA = Yatt + (size_t)(b * NT + qrowA) * NC + h * HD;
    unsigned short* yrowB = Yatt + (size_t)(b * NT + qrowB) * NC + h * HD;
    #pragma unroll
    for (int n = 0; n < 8; ++n) {
      uint32_t u0, u1;
      asm("v_cvt_pk_bf16_f32 %0, %1, %2" : "=v"(u0) : "v"(ytA[n][0] * invA), "v"(ytA[n][1] * invA));
      asm("v_cvt_pk_bf16_f32 %0, %1, %2" : "=v"(u1) : "v"(ytA[n][2] * invA), "v"(ytA[n][3] * invA));
      uint2 pk; pk.x = u0; pk.y = u1;
      *(uint2*)(yrowA + n * 16 + lg * 4) = pk;
      asm("v_cvt_pk_bf16_f32 %0, %1, %2" : "=v"(u0) : "v"(ytB[n][0] * invB), "v"(ytB[n][1] * invB));
      asm("v_cvt_pk_bf16_f32 %0, %1, %2" : "=v"(u1) : "v"(ytB[n][2] * invB), "v"(ytB[n][3] * invB));
      pk.x = u0; pk.y = u1;
      *(uint2*)(yrowB + n * 16 + lg * 4) = pk;
    }
  }
}

extern "C" void kernel_launch(void* const* d_in, const int* in_sizes, int n_in,
                              void* d_out, int out_size, void* d_ws, size_t ws_size,
                              hipStream_t stream) {
  (void)in_sizes; (void)n_in; (void)out_size; (void)ws_size;
  const float* x     = (const float*)d_in[0];
  const float* Wqkv  = (const float*)d_in[1];
  const float* bqkv  = (const float*)d_in[2];
  const float* Wproj = (const float*)d_in[3];
  const float* bproj = (const float*)d_in[4];
  float* out = (float*)d_out;
  char* ws = (char*)d_ws;

  // workspace layout (160 MB total)
  unsigned short* xb     = (unsigned short*)(ws);               // 32MB  [BT][NC] bf16
  unsigned short* WqkvT  = (unsigned short*)(ws + 33554432);    // 24MB  [6144][2048]
  unsigned short* WprojT = (unsigned short*)(ws + 58720256);    // 8MB   [2048][2048]
  unsigned short* Qb     = (unsigned short*)(ws + 67108864);    // 32MB  [BH][T][D]
  unsigned short* Kb     = (unsigned short*)(ws + 100663296);   // 32MB
  unsigned short* Vb     = (unsigned short*)(ws + 134217728);   // 32MB
  unsigned short* att    = xb;  // reuse (xb dead after GEMM1)

  k_prep<<<dim3(12288), dim3(256), 0, stream>>>(x, xb, Wqkv, WqkvT, Wproj, WprojT);
  k_gemm_bt2<0><<<dim3(48, 32), dim3(256), 0, stream>>>(xb, WqkvT, bqkv, nullptr, Qb, Kb, Vb, BT, 3 * NC, NC);
  k_attn<<<dim3(64, 8), dim3(256), 0, stream>>>(Qb, Kb, Vb, att);
  k_gemm_bt2<1><<<dim3(16, 32), dim3(256), 0, stream>>>(att, WprojT, bproj, out, nullptr, nullptr, nullptr, BT, NC, NC);
}

// Round 16
// 392.347 us; speedup vs baseline: 1.0185x; 1.0185x over previous
//
#include <hip/hip_runtime.h>
#include <hip/hip_bf16.h>
#include <stdint.h>
#include <math.h>

// Problem constants
#define NB 4
#define NT 2048
#define NC 2048
#define NH 16
#define HD 128
#define BT (NB*NT)   // 8192

typedef __attribute__((ext_vector_type(8))) short s16x8;
typedef __attribute__((ext_vector_type(4))) short s16x4;
typedef __attribute__((ext_vector_type(4))) float f32x4;

typedef __attribute__((address_space(1))) void as1_void;
typedef __attribute__((address_space(3))) void as3_void;

static __device__ __forceinline__ unsigned short f2bf(float f) {
  union { float f; uint32_t u; } v; v.f = f;
  return (unsigned short)((v.u + 0x7fffu + ((v.u >> 16) & 1u)) >> 16);
}
static __device__ __forceinline__ float bf2f(unsigned short u) {
  union { uint32_t u; float f; } v; v.u = ((uint32_t)u) << 16;
  return v.f;
}
static __device__ __forceinline__ void async16(unsigned short* lds, const unsigned short* g) {
  __builtin_amdgcn_global_load_lds((as1_void*)g, (as3_void*)lds, 16, 0, 0);
}
static __device__ __forceinline__ uint32_t lds_off(void* p) {
  return (uint32_t)(size_t)(as3_void*)p;
}

// ---------------- fused prep: convert x->bf16  +  transpose Wqkv, Wproj ----------------
__global__ void k_prep(const float* __restrict__ x, unsigned short* __restrict__ xb,
                       const float* __restrict__ Wqkv, unsigned short* __restrict__ WqkvT,
                       const float* __restrict__ Wproj, unsigned short* __restrict__ WprojT) {
  __shared__ unsigned short tile[64][65];
  const int blk = blockIdx.x;
  const int t = threadIdx.x;
  if (blk < 8192) {
    // convert: 8 elems/thread
    const int i = blk * 256 + t;
    const float4* p = (const float4*)x + (size_t)i * 2;
    float4 a = p[0], b = p[1];
    union { unsigned short s[8]; uint4 u; } o;
    o.s[0] = f2bf(a.x); o.s[1] = f2bf(a.y); o.s[2] = f2bf(a.z); o.s[3] = f2bf(a.w);
    o.s[4] = f2bf(b.x); o.s[5] = f2bf(b.y); o.s[6] = f2bf(b.z); o.s[7] = f2bf(b.w);
    ((uint4*)xb)[i] = o.u;
    return;
  }
  const float* W;
  unsigned short* WT;
  int bx, by, N;
  if (blk < 8192 + 3072) {
    const int id = blk - 8192;
    W = Wqkv; WT = WqkvT; N = 3 * NC; bx = id % 96; by = id / 96;
  } else {
    const int id = blk - 11264;
    W = Wproj; WT = WprojT; N = NC; bx = id % 32; by = id / 32;
  }
  const int K = NC;
  const int k0 = by * 64, n0 = bx * 64;
  const int jj = t & 63, base_i = t >> 6;
  #pragma unroll
  for (int p = 0; p < 16; ++p) {
    int i = p * 4 + base_i;
    tile[i][jj] = f2bf(W[(size_t)(k0 + i) * N + n0 + jj]);
  }
  __syncthreads();
  #pragma unroll
  for (int p = 0; p < 16; ++p) {
    int j = p * 4 + base_i;
    WT[(size_t)(n0 + j) * K + k0 + jj] = tile[jj][j];
  }
}

// ---------------- GEMM 256x128 block, BK=64, 256 thr / 4 waves (4Mx1N) ----------------
// FROZEN staging/core (session GEMM optimum): LDS 48 KiB, 2 blocks/CU, 2-phase
// __syncthreads, chunk-XOR swizzle (0 conflicts), natural blockIdx.
// Wave grid 4Mx1N: wave tile 64 rows x 128 cols — same 42.7 FLOP/LDS-byte and
// 32 MFMA/kk as 2Mx2N, but each wave owns the FULL d-range, so the RoPE pair
// (d, d+64) = (acc[mi][ni], acc[mi][ni+4]) is register-local: the fused rope
// epilogue needs NO barriers / NO LDS exchange (r14's +10.5us tax removed).
// __launch_bounds__(256,2) MANDATORY (r3/r8 spills). Structural ledger: r5
// 4-phase, r6 256², r12 ring-3 all regressed — do not re-attempt without m201.
// MODE 0: scatter bf16 Q/K/V [B][H][T][D], fused RoPE on Q/K (one __sincosf per
// (mi,ni) + rotation recurrence over r; tp never crosses a 2048 boundary).
// MODE 1: fp32 row-major out.
template<int MODE>
__global__ __launch_bounds__(256, 2)
void k_gemm_bt2(const unsigned short* __restrict__ A,
                const unsigned short* __restrict__ Bt,
                const float* __restrict__ bias,
                float* __restrict__ OutF,
                unsigned short* __restrict__ Qd,
                unsigned short* __restrict__ Kd,
                unsigned short* __restrict__ Vd,
                int M, int N, int K)
{
  __shared__ __align__(16) unsigned short Al[256 * 64];
  __shared__ __align__(16) unsigned short Bl[128 * 64];
  const int t = threadIdx.x;
  const int l = t & 63;
  const int wm = t >> 6;                   // 4 x 1 wave grid; wave tile 64x128
  const int bm = blockIdx.y * 256, bn = blockIdx.x * 128;
  const int lr = l & 15, lg = l >> 4;

  f32x4 acc[4][8];
  #pragma unroll
  for (int i = 0; i < 4; ++i)
    #pragma unroll
    for (int j = 0; j < 8; ++j)
      acc[i][j] = f32x4{0.f, 0.f, 0.f, 0.f};

  for (int k0 = 0; k0 < K; k0 += 64) {
    // stage A 256x64 (2048 chunks, 8 rounds) + B 128x64 (1024 chunks, 4 rounds)
    #pragma unroll
    for (int i = 0; i < 8; ++i) {
      const int Cc = i * 256 + t;          // 16B chunk id
      const int row = Cc >> 3;
      const int kc = (Cc & 7) ^ (row & 7);
      async16(&Al[(i * 256 + (t & 192)) * 8], &A[(size_t)(bm + row) * K + k0 + kc * 8]);
    }
    #pragma unroll
    for (int i = 0; i < 4; ++i) {
      const int Cc = i * 256 + t;
      const int row = Cc >> 3;
      const int kc = (Cc & 7) ^ (row & 7);
      async16(&Bl[(i * 256 + (t & 192)) * 8], &Bt[(size_t)(bn + row) * K + k0 + kc * 8]);
    }
    __syncthreads();
    #pragma unroll
    for (int kk = 0; kk < 2; ++kk) {
      s16x8 af[4], bfr[8];
      #pragma unroll
      for (int mi = 0; mi < 4; ++mi) {
        const int row = wm * 64 + mi * 16 + lr;
        const int ch = (kk * 4 + lg) ^ (row & 7);
        af[mi] = *(const s16x8*)&Al[row * 64 + ch * 8];
      }
      #pragma unroll
      for (int ni = 0; ni < 8; ++ni) {
        const int row = ni * 16 + lr;
        const int ch = (kk * 4 + lg) ^ (row & 7);
        bfr[ni] = *(const s16x8*)&Bl[row * 64 + ch * 8];
      }
      __builtin_amdgcn_s_setprio(1);
      #pragma unroll
      for (int mi = 0; mi < 4; ++mi)
        #pragma unroll
        for (int ni = 0; ni < 8; ++ni)
          acc[mi][ni] = __builtin_amdgcn_mfma_f32_16x16x32_bf16(af[mi], bfr[ni], acc[mi][ni], 0, 0, 0);
      __builtin_amdgcn_s_setprio(0);
    }
    __syncthreads();
  }

  // epilogue; C/D layout: col = lane&15, row = (lane>>4)*4 + reg  [m89-verified]
  if (MODE == 1) {
    #pragma unroll
    for (int mi = 0; mi < 4; ++mi) {
      #pragma unroll
      for (int ni = 0; ni < 8; ++ni) {
        const int col = bn + ni * 16 + lr;
        const float bv = bias[col];
        #pragma unroll
        for (int r = 0; r < 4; ++r) {
          const int row = bm + wm * 64 + mi * 16 + lg * 4 + r;
          OutF[(size_t)row * N + col] = acc[mi][ni][r] + bv;
        }
      }
    }
  } else {
    const int whichB = bn >> 11;            // 0=q 1=k 2=v (block-uniform: panel 128-aligned)
    const int bb = bm >> 11;                // batch (block-uniform: 2048%256==0)
    const int h = (bn & 2047) >> 7;         // head (block-uniform)
    unsigned short* dst = (whichB == 0) ? Qd : (whichB == 1 ? Kd : Vd);
    if (whichB == 2) {
      // V: plain scatter
      #pragma unroll
      for (int mi = 0; mi < 4; ++mi) {
        #pragma unroll
        for (int ni = 0; ni < 8; ++ni) {
          const float bv = bias[bn + ni * 16 + lr];
          const int d = ni * 16 + lr;
          #pragma unroll
          for (int r = 0; r < 4; ++r) {
            const int tp = (bm + wm * 64 + mi * 16 + lg * 4 + r) & 2047;
            dst[(((size_t)(bb * NH + h)) * NT + tp) * HD + d] = f2bf(acc[mi][ni][r] + bv);
          }
        }
      }
    } else {
      // Q/K: fused RoPE, fully register-local: pair (d, d+64) = (acc[mi][ni], acc[mi][ni+4]).
      const float qsc = (whichB == 0) ? (0.08838834764831845f * 1.4426950408889634f) : 1.0f;
      float invf[4], crot[4], srot[4];
      #pragma unroll
      for (int ni = 0; ni < 4; ++ni) {
        invf[ni] = exp2f(-(float)(ni * 16 + lr) * 0.2076205059304602f);  // log2(10000)/64
        __sincosf(invf[ni], &srot[ni], &crot[ni]);   // per-step rotation (delta tp = 1)
      }
      #pragma unroll
      for (int mi = 0; mi < 4; ++mi) {
        const int tpb = (bm + wm * 64 + mi * 16 + lg * 4) & 2047;
        #pragma unroll
        for (int ni = 0; ni < 4; ++ni) {
          const int dlo = ni * 16 + lr;
          const float bvlo = bias[bn + dlo];
          const float bvhi = bias[bn + dlo + 64];
          float s, c;
          __sincosf((float)tpb * invf[ni], &s, &c);
          #pragma unroll
          for (int r = 0; r < 4; ++r) {
            const int tp = tpb + r;         // same 16-block: no 2048 wrap possible
            const float lo = acc[mi][ni][r] + bvlo;
            const float hi = acc[mi][ni + 4][r] + bvhi;
            const size_t base = (((size_t)(bb * NH + h)) * NT + tp) * HD;
            dst[base + dlo]      = f2bf((lo * c - hi * s) * qsc);
            dst[base + dlo + 64] = f2bf((hi * c + lo * s) * qsc);
            const float cn = c * crot[ni] - s * srot[ni];   // rotate by invf[ni]
            s = s * crot[ni] + c * srot[ni];
            c = cn;
          }
        }
      }
    }
  }
}

// ---------------- flash attention: 4 waves x 32 q-rows (2 frags), KV tile 64, dbuf ----------------
// Each lane owns TWO q-rows; K-frag LDS reads, V tr-reads, and KV staging SHARED
// across both fragments. Block = 128 q-rows; grid (bh 64, pair 8); pair balance
// (i, 15-i) -> 34 kv-iters const; same-head blocks on one XCD.
// swapped S^T = mfma(K, Q); T13 defer-max; cvt_pk P-pack; packed 8B output stores.
// Final tile skipped by waves 0,1 (fully causal-masked there — exact-zero contribution).
__global__ __launch_bounds__(256, 2)
void k_attn(const unsigned short* __restrict__ Q,
            const unsigned short* __restrict__ Kg,
            const unsigned short* __restrict__ Vg,
            unsigned short* __restrict__ Yatt)   // att [BT][NC] bf16
{
  __shared__ __align__(16) unsigned short Kl[2][64 * 128];  // [key][d], 16B-chunk-swizzled
  __shared__ __align__(16) unsigned short Vl[2][64 * 128];  // subtiled [key/4][d/16][4][16]
  const int bh = blockIdx.x;          // 0..63
  const int pair = blockIdx.y;        // 0..7
  const int b = bh >> 4, h = bh & 15;
  const int t = threadIdx.x, l = t & 63, wv = t >> 6;
  const int lr = l & 15, lg = l >> 4;
  const size_t hoff = (size_t)bh * NT * HD;
  const unsigned short* Qh = Q + hoff;
  const unsigned short* Kh = Kg + hoff;
  const unsigned short* Vh = Vg + hoff;
  const uint32_t vbase0 = lds_off(&Vl[0][0]);

  auto stageKV = [&](int buf, int kv0) {
    #pragma unroll
    for (int i = 0; i < 4; ++i) {
      const int Cc = i * 256 + t;
      {  // K tile: row-major [64][128], 16B chunks swizzled with (row&7)
        const int krow = Cc >> 4;
        const int kc = (Cc & 15) ^ (krow & 7);
        async16(&Kl[buf][(i * 256 + (t & 192)) * 8], &Kh[(size_t)(kv0 + krow) * HD + kc * 8]);
      }
      {  // V tile: subtile S = kq*8+dq holds [4 keys][16 d] row-major
        const int S = Cc >> 3, c8 = Cc & 7;
        const int kq = S >> 3, dq = S & 7;
        const int vk = kq * 4 + (c8 >> 1), vd = dq * 16 + (c8 & 1) * 8;
        async16(&Vl[buf][(i * 256 + (t & 192)) * 8], &Vh[(size_t)(kv0 + vk) * HD + vd]);
      }
    }
  };

  #pragma unroll 1
  for (int rep = 0; rep < 2; ++rep) {
    const int qb16 = rep ? (15 - pair) : pair;   // q-tile of 128 rows
    const int q0w = qb16 * 128 + wv * 32;        // wave's 32-row strip
    const int qrowA = q0w + lr, qrowB = q0w + 16 + lr;

    __syncthreads();  // protect LDS reuse across reps

    s16x8 qfA[4], qfB[4];
    #pragma unroll
    for (int m = 0; m < 4; ++m) {
      qfA[m] = *(const s16x8*)(Qh + (size_t)qrowA * HD + m * 32 + lg * 8);
      qfB[m] = *(const s16x8*)(Qh + (size_t)qrowB * HD + m * 32 + lg * 8);
    }

    f32x4 ytA[8], ytB[8];
    #pragma unroll
    for (int n = 0; n < 8; ++n) { ytA[n] = f32x4{0.f,0.f,0.f,0.f}; ytB[n] = f32x4{0.f,0.f,0.f,0.f}; }
    float mrunA = -1e30f, lrunA = 0.f, mrunB = -1e30f, lrunB = 0.f;

    auto computeTile = [&](int buf, int kv0) {
      // S^T tiles for both q-frags; K frags shared
      f32x4 stA[4], stB[4];
      __builtin_amdgcn_s_setprio(1);
      #pragma unroll
      for (int kt = 0; kt < 4; ++kt) {
        f32x4 a = f32x4{0.f,0.f,0.f,0.f}, bq = f32x4{0.f,0.f,0.f,0.f};
        const int krow = kt * 16 + lr;
        #pragma unroll
        for (int m = 0; m < 4; ++m) {
          const int ch = (m * 4 + lg) ^ (krow & 7);
          s16x8 kf = *(const s16x8*)&Kl[buf][krow * 128 + ch * 8];
          a  = __builtin_amdgcn_mfma_f32_16x16x32_bf16(kf, qfA[m], a, 0, 0, 0);
          bq = __builtin_amdgcn_mfma_f32_16x16x32_bf16(kf, qfB[m], bq, 0, 0, 0);
        }
        stA[kt] = a; stB[kt] = bq;
      }
      __builtin_amdgcn_s_setprio(0);

      // causal mask near diagonal (per frag)
      if (kv0 + 63 > q0w) {
        #pragma unroll
        for (int kt = 0; kt < 4; ++kt)
          #pragma unroll
          for (int r = 0; r < 4; ++r) {
            const int key = kv0 + kt * 16 + lg * 4 + r;
            if (key > qrowA) stA[kt][r] = -3.0e38f;
            if (key > qrowB) stB[kt][r] = -3.0e38f;
          }
      }

      // online softmax x2 (T13 defer-max)
      float tmA = -3.0e38f, tmB = -3.0e38f;
      #pragma unroll
      for (int kt = 0; kt < 4; ++kt)
        #pragma unroll
        for (int r = 0; r < 4; ++r) { tmA = fmaxf(tmA, stA[kt][r]); tmB = fmaxf(tmB, stB[kt][r]); }
      tmA = fmaxf(tmA, __shfl_xor(tmA, 16)); tmA = fmaxf(tmA, __shfl_xor(tmA, 32));
      tmB = fmaxf(tmB, __shfl_xor(tmB, 16)); tmB = fmaxf(tmB, __shfl_xor(tmB, 32));
      if (!__all((tmA - mrunA <= 8.0f) && (tmB - mrunB <= 8.0f))) {
        const float mnA = fmaxf(mrunA, tmA), mnB = fmaxf(mrunB, tmB);
        const float fsA = exp2f(mrunA - mnA), fsB = exp2f(mrunB - mnB);
        mrunA = mnA; mrunB = mnB;
        lrunA *= fsA; lrunB *= fsB;
        #pragma unroll
        for (int n = 0; n < 8; ++n)
          #pragma unroll
          for (int r = 0; r < 4; ++r) { ytA[n][r] *= fsA; ytB[n][r] *= fsB; }
      }

      float pvA[16], pvB[16];
      float psA = 0.f, psB = 0.f;
      #pragma unroll
      for (int kt = 0; kt < 4; ++kt)
        #pragma unroll
        for (int r = 0; r < 4; ++r) {
          const float pa = exp2f(stA[kt][r] - mrunA);
          const float pb = exp2f(stB[kt][r] - mrunB);
          psA += pa; psB += pb;
          pvA[kt * 4 + r] = pa; pvB[kt * 4 + r] = pb;
        }
      lrunA += psA; lrunB += psB;

      // pack P^T frags via v_cvt_pk_bf16_f32
      union { uint32_t w[4]; s16x8 v; } puA[2], puB[2];
      #pragma unroll
      for (int gk = 0; gk < 2; ++gk)
        #pragma unroll
        for (int w = 0; w < 4; ++w) {
          const int i0 = (gk * 2 + (w >> 1)) * 4 + (w & 1) * 2;
          asm("v_cvt_pk_bf16_f32 %0, %1, %2" : "=v"(puA[gk].w[w]) : "v"(pvA[i0]), "v"(pvA[i0 + 1]));
          asm("v_cvt_pk_bf16_f32 %0, %1, %2" : "=v"(puB[gk].w[w]) : "v"(pvB[i0]), "v"(pvB[i0 + 1]));
        }

      // PV: V^T frags shared across both q-frags
      const uint32_t vb = vbase0 + (uint32_t)buf * 16384;
      #pragma unroll
      for (int gk = 0; gk < 2; ++gk) {
        s16x4 va[8], vb2[8];
        #pragma unroll
        for (int n = 0; n < 8; ++n) {
          const uint32_t a0 = vb + ((uint32_t)((gk * 8 + lg) * 8 + n)) * 128 + (uint32_t)lr * 8;
          asm volatile("ds_read_b64_tr_b16 %0, %1" : "=v"(va[n])  : "v"(a0));
          asm volatile("ds_read_b64_tr_b16 %0, %1" : "=v"(vb2[n]) : "v"(a0 + 4096));
        }
        asm volatile("s_waitcnt lgkmcnt(0)" ::: "memory");
        __builtin_amdgcn_sched_barrier(0);
        __builtin_amdgcn_s_setprio(1);
        #pragma unroll
        for (int n = 0; n < 8; ++n) {
          s16x8 vf;
          vf[0] = va[n][0];  vf[1] = va[n][1];  vf[2] = va[n][2];  vf[3] = va[n][3];
          vf[4] = vb2[n][0]; vf[5] = vb2[n][1]; vf[6] = vb2[n][2]; vf[7] = vb2[n][3];
          ytA[n] = __builtin_amdgcn_mfma_f32_16x16x32_bf16(vf, puA[gk].v, ytA[n], 0, 0, 0);
          ytB[n] = __builtin_amdgcn_mfma_f32_16x16x32_bf16(vf, puB[gk].v, ytB[n], 0, 0, 0);
        }
        __builtin_amdgcn_s_setprio(0);
      }
    };

    const int nkv = 2 * qb16 + 2;
    stageKV(0, 0);
    asm volatile("s_waitcnt vmcnt(0)" ::: "memory");
    __syncthreads();
    int buf = 0;
    #pragma unroll 1
    for (int kv = 0; kv < nkv - 1; ++kv) {
      stageKV(buf ^ 1, (kv + 1) * 64);      // issue next tile's loads first
      computeTile(buf, kv * 64);            // overlap compute with loads
      asm volatile("s_waitcnt vmcnt(0)" ::: "memory");
      __builtin_amdgcn_s_barrier();
      buf ^= 1;
    }
    if ((nkv - 1) * 64 <= q0w + 31)         // waves 0,1: final tile fully masked -> skip
      computeTile(buf, (nkv - 1) * 64);

    // finalize both frags: reduce l, scale, packed 8B stores
    lrunA += __shfl_xor(lrunA, 16); lrunA += __shfl_xor(lrunA, 32);
    lrunB += __shfl_xor(lrunB, 16); lrunB += __shfl_xor(lrunB, 32);
    const float invA = 1.f / lrunA, invB = 1.f / lrunB;
    unsigned short* yrowA = Yatt + (size_t)(b * NT + qrowA) * NC + h * HD;
    unsigned short* yrowB = Yatt + (size_t)(b * NT + qrowB) * NC + h * HD;
    #pragma unroll
    for (int n = 0; n < 8; ++n) {
      uint32_t u0, u1;
      asm("v_cvt_pk_bf16_f32 %0, %1, %2" : "=v"(u0) : "v"(ytA[n][0] * invA), "v"(ytA[n][1] * invA));
      asm("v_cvt_pk_bf16_f32 %0, %1, %2" : "=v"(u1) : "v"(ytA[n][2] * invA), "v"(ytA[n][3] * invA));
      uint2 pk; pk.x = u0; pk.y = u1;
      *(uint2*)(yrowA + n * 16 + lg * 4) = pk;
      asm("v_cvt_pk_bf16_f32 %0, %1, %2" : "=v"(u0) : "v"(ytB[n][0] * invB), "v"(ytB[n][1] * invB));
      asm("v_cvt_pk_bf16_f32 %0, %1, %2" : "=v"(u1) : "v"(ytB[n][2] * invB), "v"(ytB[n][3] * invB));
      pk.x = u0; pk.y = u1;
      *(uint2*)(yrowB + n * 16 + lg * 4) = pk;
    }
  }
}

extern "C" void kernel_launch(void* const* d_in, const int* in_sizes, int n_in,
                              void* d_out, int out_size, void* d_ws, size_t ws_size,
                              hipStream_t stream) {
  (void)in_sizes; (void)n_in; (void)out_size; (void)ws_size;
  const float* x     = (const float*)d_in[0];
  const float* Wqkv  = (const float*)d_in[1];
  const float* bqkv  = (const float*)d_in[2];
  const float* Wproj = (const float*)d_in[3];
  const float* bproj = (const float*)d_in[4];
  float* out = (float*)d_out;
  char* ws = (char*)d_ws;

  // workspace layout (160 MB total)
  unsigned short* xb     = (unsigned short*)(ws);               // 32MB  [BT][NC] bf16
  unsigned short* WqkvT  = (unsigned short*)(ws + 33554432);    // 24MB  [6144][2048]
  unsigned short* WprojT = (unsigned short*)(ws + 58720256);    // 8MB   [2048][2048]
  unsigned short* Qb     = (unsigned short*)(ws + 67108864);    // 32MB  [BH][T][D]
  unsigned short* Kb     = (unsigned short*)(ws + 100663296);   // 32MB
  unsigned short* Vb     = (unsigned short*)(ws + 134217728);   // 32MB
  unsigned short* att    = xb;  // reuse (xb dead after GEMM1)

  k_prep<<<dim3(12288), dim3(256), 0, stream>>>(x, xb, Wqkv, WqkvT, Wproj, WprojT);
  k_gemm_bt2<0><<<dim3(48, 32), dim3(256), 0, stream>>>(xb, WqkvT, bqkv, nullptr, Qb, Kb, Vb, BT, 3 * NC, NC);
  k_attn<<<dim3(64, 8), dim3(256), 0, stream>>>(Qb, Kb, Vb, att);
  k_gemm_bt2<1><<<dim3(16, 32), dim3(256), 0, stream>>>(att, WprojT, bproj, out, nullptr, nullptr, nullptr, BT, NC, NC);
}